// Round 2
// baseline (652.364 us; speedup 1.0000x reference)
//
#include <hip/hip_runtime.h>
#include <hip/hip_bf16.h>

typedef __attribute__((ext_vector_type(8))) short s8v;
typedef __attribute__((ext_vector_type(4))) float f4v;
typedef __hip_bfloat16 bf16;

// ---- problem constants ----
#define BSZ 4
#define SEQ 1024
#define IDIM 4096
#define RNK 512
#define RPD 64
#define NH 32
#define HD 128
#define BT 4096   // BSZ*SEQ tokens

__device__ __forceinline__ void load_lds16(const bf16* g, bf16* l) {
  __builtin_amdgcn_global_load_lds((const __attribute__((address_space(1))) void*)g,
                                   (__attribute__((address_space(3))) void*)l, 16, 0, 0);
}

// =====================================================================
// Generic bf16 MFMA GEMM:  C[m,n] = sum_k A[m,k] * B[n,k]  (+bias[n]) (+addend[m,n])
// A: (M x K) row-major lda ; B: (N x K) row-major ldb ; C row-major ldc.
// Batched over blockIdx.z: z1 = z / nz2, z2 = z % nz2; pointer offsets via strides.
// Requires M%BM==0, N%BN==0, K%32==0, 16B-aligned rows (lda/ldb multiples of 8).
// =====================================================================
template<int BM, int BN, int WTM, int WTN, int OUT_BF16, int ADD_MODE, int HAS_BIAS>
__global__ __launch_bounds__(256) void gemm_bt(
    const bf16* __restrict__ A, const bf16* __restrict__ B, void* __restrict__ Cv,
    const float* __restrict__ bias, const void* __restrict__ addend,
    int K, int lda, int ldb, int ldc, int ldadd, int nz2,
    long long sA1, long long sA2, long long sB1, long long sB2,
    long long sC1, long long sC2, long long sD1, long long sD2)
{
  constexpr int BK = 32;
  constexpr int WM = BM / WTM, WN = BN / WTN;
  constexpr int FM = WM / 16, FN = WN / 16;
  static_assert(WTM * WTN == 4, "4 waves / 256 threads");
  static_assert((BM * BK) % 2048 == 0 && (BN * BK) % 2048 == 0, "staging coverage");
  __shared__ alignas(16) bf16 As[BM * BK];
  __shared__ alignas(16) bf16 Bs[BN * BK];

  int z = blockIdx.z;
  int z1 = z / nz2, z2 = z - z1 * nz2;
  A += z1 * sA1 + z2 * sA2;
  B += z1 * sB1 + z2 * sB2;
  long long coff = z1 * sC1 + z2 * sC2;
  long long doffz = z1 * sD1 + z2 * sD2;

  int tid = threadIdx.x;
  int lane = tid & 63, wave = tid >> 6;
  int wr = wave / WTN, wc = wave % WTN;
  int rowBase = blockIdx.y * BM;
  int colBase = blockIdx.x * BN;

  f4v acc[FM][FN];
  #pragma unroll
  for (int i = 0; i < FM; ++i)
    #pragma unroll
    for (int j = 0; j < FN; ++j) acc[i][j] = {0.f, 0.f, 0.f, 0.f};

  constexpr int A_LOADS = (BM * BK) / 2048;
  constexpr int B_LOADS = (BN * BK) / 2048;
  int lrow = lane & 15, lk = (lane >> 4) * 8;

  for (int k0 = 0; k0 < K; k0 += BK) {
    #pragma unroll
    for (int i = 0; i < A_LOADS; ++i) {
      int e = tid * 8 + i * 2048;
      load_lds16(A + (long long)(rowBase + (e >> 5)) * lda + k0 + (e & 31), &As[e]);
    }
    #pragma unroll
    for (int i = 0; i < B_LOADS; ++i) {
      int e = tid * 8 + i * 2048;
      load_lds16(B + (long long)(colBase + (e >> 5)) * ldb + k0 + (e & 31), &Bs[e]);
    }
    __syncthreads();   // compiler drains vmcnt before s_barrier

    s8v av[FM], bv[FN];
    #pragma unroll
    for (int fm = 0; fm < FM; ++fm)
      av[fm] = *(const s8v*)&As[(wr * WM + fm * 16 + lrow) * BK + lk];
    #pragma unroll
    for (int fn = 0; fn < FN; ++fn)
      bv[fn] = *(const s8v*)&Bs[(wc * WN + fn * 16 + lrow) * BK + lk];
    #pragma unroll
    for (int fm = 0; fm < FM; ++fm)
      #pragma unroll
      for (int fn = 0; fn < FN; ++fn)
        acc[fm][fn] = __builtin_amdgcn_mfma_f32_16x16x32_bf16(av[fm], bv[fn], acc[fm][fn], 0, 0, 0);
    __syncthreads();
  }

  bf16* Cb = (bf16*)Cv;
  float* Cf = (float*)Cv;
  const float* addf = (const float*)addend;
  const bf16* addb = (const bf16*)addend;
  int lcol = lane & 15, lr4 = (lane >> 4) * 4;
  #pragma unroll
  for (int fm = 0; fm < FM; ++fm) {
    #pragma unroll
    for (int fn = 0; fn < FN; ++fn) {
      int col = colBase + wc * WN + fn * 16 + lcol;
      #pragma unroll
      for (int j = 0; j < 4; ++j) {
        int row = rowBase + wr * WM + fm * 16 + lr4 + j;
        float v = acc[fm][fn][j];
        if (HAS_BIAS) v += bias[col];
        if (ADD_MODE == 1) v += addf[doffz + (long long)row * ldadd + col];
        if (ADD_MODE == 2) v += __bfloat162float(addb[doffz + (long long)row * ldadd + col]);
        long long idx = coff + (long long)row * ldc + col;
        if (OUT_BF16) Cb[idx] = __float2bfloat16(v);
        else          Cf[idx] = v;
      }
    }
  }
}

// ---------------- elementwise / helper kernels ----------------

__global__ void cast4(const float* __restrict__ in, bf16* __restrict__ out, int n4) {
  int i = blockIdx.x * 256 + threadIdx.x;
  if (i >= n4) return;
  float4 v = ((const float4*)in)[i];
  union { ushort4 u; bf16 h[4]; } o;
  o.h[0] = __float2bfloat16(v.x); o.h[1] = __float2bfloat16(v.y);
  o.h[2] = __float2bfloat16(v.z); o.h[3] = __float2bfloat16(v.w);
  ((ushort4*)out)[i] = o.u;
}

// 32x32-tile bf16 transpose: in (R x C) -> out (C x R), batched over z
__global__ __launch_bounds__(256) void tr_bf16(const bf16* __restrict__ in, bf16* __restrict__ out,
                                               int R, int C) {
  __shared__ bf16 t[32][33];
  long long zo = (long long)blockIdx.z * R * C;
  int c0 = blockIdx.x * 32, r0 = blockIdx.y * 32;
  int tx = threadIdx.x & 31, ty = threadIdx.x >> 5;   // 32 x 8
  #pragma unroll
  for (int i = 0; i < 32; i += 8)
    t[ty + i][tx] = in[zo + (long long)(r0 + ty + i) * C + (c0 + tx)];
  __syncthreads();
  #pragma unroll
  for (int i = 0; i < 32; i += 8)
    out[zo + (long long)(c0 + ty + i) * R + (r0 + tx)] = t[tx][ty + i];
}

__device__ __forceinline__ float block_sum256(float v) {
  #pragma unroll
  for (int o = 32; o > 0; o >>= 1) v += __shfl_xor(v, o, 64);
  __shared__ float red[4];
  int lane = threadIdx.x & 63, w = threadIdx.x >> 6;
  if (lane == 0) red[w] = v;
  __syncthreads();
  return red[0] + red[1] + red[2] + red[3];
}

// dkv row (len 576 fp32): rmsnorm first 512 -> ckv bf16 ; rope last 64 -> kr bf16
__global__ __launch_bounds__(256) void rms_dkv(const float* __restrict__ dkv,
    const float* __restrict__ w, const float* __restrict__ ch, const float* __restrict__ sh,
    bf16* __restrict__ ckv, bf16* __restrict__ kr) {
  int row = blockIdx.x, t = threadIdx.x;
  const float* xr = dkv + (long long)row * 576;
  float v0 = xr[t], v1 = xr[t + 256];
  float ss = block_sum256(v0 * v0 + v1 * v1);
  float sc = rsqrtf(ss * (1.0f / 512.0f) + 1.1920929e-07f);
  long long o = (long long)row * 512;
  ckv[o + t]       = __float2bfloat16(v0 * sc * w[t]);
  ckv[o + t + 256] = __float2bfloat16(v1 * sc * w[t + 256]);
  if (t < 64) {
    int s = row & (SEQ - 1);
    float a = xr[512 + t], r;
    if (t < 32) r = a * ch[s * 32 + t]      - xr[512 + t + 32] * sh[s * 32 + t];
    else        r = a * ch[s * 32 + t - 32] + xr[512 + t - 32] * sh[s * 32 + t - 32];
    kr[(long long)row * 64 + t] = __float2bfloat16(r);
  }
}

__global__ __launch_bounds__(256) void rms512(const float* __restrict__ in,
    const float* __restrict__ w, bf16* __restrict__ out) {
  int row = blockIdx.x, t = threadIdx.x;
  const float* xr = in + (long long)row * 512;
  float v0 = xr[t], v1 = xr[t + 256];
  float ss = block_sum256(v0 * v0 + v1 * v1);
  float sc = rsqrtf(ss * (1.0f / 512.0f) + 1.1920929e-07f);
  long long o = (long long)row * 512;
  out[o + t]       = __float2bfloat16(v0 * sc * w[t]);
  out[o + t + 256] = __float2bfloat16(v1 * sc * w[t + 256]);
}

__global__ void rope_qr(const float* __restrict__ in, const float* __restrict__ ch,
                        const float* __restrict__ sh, bf16* __restrict__ out) {
  int row = blockIdx.x, t = threadIdx.x;   // 64 threads
  const float* xr = in + (long long)row * 64;
  int s = row & (SEQ - 1);
  float a = xr[t], r;
  if (t < 32) r = a * ch[s * 32 + t]      - xr[t + 32] * sh[s * 32 + t];
  else        r = a * ch[s * 32 + t - 32] + xr[t - 32] * sh[s * 32 + t - 32];
  out[(long long)row * 64 + t] = __float2bfloat16(r);
}

// =====================================================================
extern "C" void kernel_launch(void* const* d_in, const int* in_sizes, int n_in,
                              void* d_out, int out_size, void* d_ws, size_t ws_size,
                              hipStream_t stream) {
  const float* x    = (const float*)d_in[0];
  const float* ch   = (const float*)d_in[1];
  const float* sh   = (const float*)d_in[2];
  const float* mask = (const float*)d_in[3];
  const float* wdkv = (const float*)d_in[4];
  const float* bdkv = (const float*)d_in[5];
  const float* kvnw = (const float*)d_in[6];
  const float* wdq  = (const float*)d_in[7];
  const float* bdq  = (const float*)d_in[8];
  const float* qnw  = (const float*)d_in[9];
  const float* wuq  = (const float*)d_in[10];
  const float* buq  = (const float*)d_in[11];
  const float* wqr  = (const float*)d_in[12];
  const float* bqr  = (const float*)d_in[13];
  const float* wuk  = (const float*)d_in[14];
  const float* wuv  = (const float*)d_in[15];
  const float* wo   = (const float*)d_in[16];
  const float* bo   = (const float*)d_in[17];
  float* out = (float*)d_out;
  (void)in_sizes; (void)n_in; (void)out_size; (void)ws_size;

  // ---------- workspace layout (total ~107 MB) ----------
  char* ws = (char*)d_ws;
  bf16* regionA = (bf16*)(ws);                       // 33,554,432 B : xb then wo_b
  bf16* outh    = (bf16*)(ws + 33554432);            // 33,554,432 B
  bf16* wdkv_b  = (bf16*)(ws + 67108864);            //  4,718,592 B
  bf16* wdq_b   = (bf16*)(ws + 71827456);            //  4,194,304 B
  bf16* wuq_b   = (bf16*)(ws + 76021760);            //  4,194,304 B
  bf16* wqr_b   = (bf16*)(ws + 80216064);            //     65,536 B
  bf16* wuv_b   = (bf16*)(ws + 80281600);            //  4,194,304 B
  bf16* wuk_b   = (bf16*)(ws + 84475904);            //  4,194,304 B
  bf16* mask_b  = (bf16*)(ws + 88670208);            //  2,097,152 B
  char* regionB = ws + 90767360;                     // 20,971,520 B
  float* dkv_f  = (float*)(regionB);                 //  9,437,184 B (phase 1)
  float* cq_pre = (float*)(regionB + 9437184);       //  8,388,608 B (phase 1)
  bf16* Eb      = (bf16*)(regionB);                  // 16,777,216 B (phase 2)
  bf16* FT      = (bf16*)(regionB + 16777216);       //  4,194,304 B (phase 2)
  // total ws use: 111,738,880 B

  bf16* xb   = regionA;          // phase 1 of regionA
  bf16* wo_b = regionA;          // phase 2 of regionA (cast after G2)

  // ---------- d_out used as scratch (64 MB); all dead before G13 ----------
  char* ob = (char*)d_out;
  bf16* qb     = (bf16*)(ob);                 // 33,554,432 B
  char* U      = ob + 33554432;
  bf16* ckv    = (bf16*)(U);                  // 4,194,304
  bf16* kr     = (bf16*)(U + 4194304);        //   524,288
  bf16* ckvT   = (bf16*)(U + 4718592);        // 4,194,304
  bf16* krT    = (bf16*)(U + 8912896);        //   524,288
  bf16* cq     = (bf16*)(U + 9437184);        // 4,194,304
  float* qr_pre= (float*)(U + 13631488);      // 1,048,576
  bf16* qr_b   = (bf16*)(U + 14680064);       //   524,288
  bf16* Gm     = (bf16*)(U + 15204352);       // 2,097,152
  bf16* Mt     = (bf16*)(U + 17301504);       //   262,144
  bf16* base_b = (bf16*)(U + 17563648);       // 4,194,304  (end 21,757,952 < 33,554,432)

  long long Z = 0;

  // ---- early casts ----
  cast4<<<dim3(16384), 256, 0, stream>>>(x, xb, 4194304);
  cast4<<<dim3(2304),  256, 0, stream>>>(wdkv, wdkv_b, 589824);
  cast4<<<dim3(2048),  256, 0, stream>>>(wdq, wdq_b, 524288);
  cast4<<<dim3(32),    256, 0, stream>>>(wqr, wqr_b, 8192);
  cast4<<<dim3(1024),  256, 0, stream>>>(mask, mask_b, 262144);

  // G1: dkv = x @ wdkv^T + b   (4096 x 576 x 4096), fp32 out
  gemm_bt<128, 64, 4, 1, 0, 0, 1><<<dim3(9, 32, 1), 256, 0, stream>>>(
      xb, wdkv_b, dkv_f, bdkv, nullptr, 4096, 4096, 4096, 576, 0, 1, Z,Z,Z,Z,Z,Z,Z,Z);
  rms_dkv<<<dim3(BT), 256, 0, stream>>>(dkv_f, kvnw, ch, sh, ckv, kr);
  tr_bf16<<<dim3(16, 32, 4), 256, 0, stream>>>(ckv, ckvT, 1024, 512);
  tr_bf16<<<dim3(2, 32, 4), 256, 0, stream>>>(kr, krT, 1024, 64);

  // G2: cq_pre = x @ wdq^T + b  (4096 x 512 x 4096), fp32   (last read of xb)
  gemm_bt<128, 128, 2, 2, 0, 0, 1><<<dim3(4, 32, 1), 256, 0, stream>>>(
      xb, wdq_b, cq_pre, bdq, nullptr, 4096, 4096, 4096, 512, 0, 1, Z,Z,Z,Z,Z,Z,Z,Z);
  rms512<<<dim3(BT), 256, 0, stream>>>(cq_pre, qnw, cq);

  // ---- late casts (after G2: regionA now free for wo_b) ----
  cast4<<<dim3(2048),  256, 0, stream>>>(wuq, wuq_b, 524288);
  cast4<<<dim3(2048),  256, 0, stream>>>(wuv, wuv_b, 524288);
  cast4<<<dim3(2048),  256, 0, stream>>>(wuk, wuk_b, 524288);
  cast4<<<dim3(16384), 256, 0, stream>>>(wo, wo_b, 4194304);

  // G3: q = cq @ wuq^T + b  (4096 x 4096 x 512), bf16 -> qb (in d_out scratch)
  gemm_bt<128, 128, 2, 2, 1, 0, 1><<<dim3(32, 32, 1), 256, 0, stream>>>(
      cq, wuq_b, qb, buq, nullptr, 512, 512, 512, 4096, 0, 1, Z,Z,Z,Z,Z,Z,Z,Z);
  // G4: qr_pre = cq @ wqr^T + b  (4096 x 64 x 512), fp32
  gemm_bt<128, 64, 4, 1, 0, 0, 1><<<dim3(1, 32, 1), 256, 0, stream>>>(
      cq, wqr_b, qr_pre, bqr, nullptr, 512, 512, 512, 64, 0, 1, Z,Z,Z,Z,Z,Z,Z,Z);
  rope_qr<<<dim3(BT), 64, 0, stream>>>(qr_pre, ch, sh, qr_b);

  // G6: G[b] = ckvT[b] @ ckvT[b]^T  (512 x 512 x 1024), z = b
  gemm_bt<128, 128, 2, 2, 1, 0, 0><<<dim3(4, 4, 4), 256, 0, stream>>>(
      ckvT, ckvT, Gm, nullptr, nullptr, 1024, 1024, 1024, 512, 0, 1,
      524288LL, Z, 524288LL, Z, 262144LL, Z, Z, Z);

  // G7: Mt[b] = ckvT[b] @ krT[b]^T  (512 x 64 x 1024), z = b
  gemm_bt<128, 64, 4, 1, 1, 0, 0><<<dim3(1, 4, 4), 256, 0, stream>>>(
      ckvT, krT, Mt, nullptr, nullptr, 1024, 1024, 1024, 64, 0, 1,
      524288LL, Z, 65536LL, Z, 32768LL, Z, Z, Z);

  // G8: base[b] = mask @ ckvT[b]^T  (1024 x 512 x 1024), z = b
  gemm_bt<128, 128, 2, 2, 1, 0, 0><<<dim3(4, 8, 4), 256, 0, stream>>>(
      mask_b, ckvT, base_b, nullptr, nullptr, 1024, 1024, 1024, 512, 0, 1,
      Z, Z, 524288LL, Z, 524288LL, Z, Z, Z);

  // G9: base[b] += qr[b] @ Mt[b]^T   (1024 x 512 x 64), in-place addend
  gemm_bt<128, 128, 2, 2, 1, 2, 0><<<dim3(4, 8, 4), 256, 0, stream>>>(
      qr_b, Mt, base_b, nullptr, base_b, 64, 64, 64, 512, 512, 1,
      65536LL, Z, 32768LL, Z, 524288LL, Z, 524288LL, Z);

  // G10: outh = base @ wuv^T  (4096 x 4096 x 512), bf16
  gemm_bt<128, 128, 2, 2, 1, 0, 0><<<dim3(32, 32, 1), 256, 0, stream>>>(
      base_b, wuv_b, outh, nullptr, nullptr, 512, 512, 512, 4096, 0, 1, Z,Z,Z,Z,Z,Z,Z,Z);

  // E[b,h] = wuv_h @ G[b]^T  (128 x 512 x 512), z = (b,h)   (regionB phase 2)
  gemm_bt<128, 128, 2, 2, 1, 0, 0><<<dim3(4, 1, 128), 256, 0, stream>>>(
      wuv_b, Gm, Eb, nullptr, nullptr, 512, 512, 512, 512, 0, 32,
      Z, 65536LL, 262144LL, Z, 2097152LL, 65536LL, Z, Z);

  // FT[b,h] = E[b,h] @ wuk_h^T  (128 x 128 x 512), z = (b,h)
  gemm_bt<128, 128, 2, 2, 1, 0, 0><<<dim3(1, 1, 128), 256, 0, stream>>>(
      Eb, wuk_b, FT, nullptr, nullptr, 512, 512, 512, 128, 0, 32,
      2097152LL, 65536LL, Z, 65536LL, 524288LL, 16384LL, Z, Z);

  // G12: outh[b,:,h*128:+128] += qb[b,:,h*128:+128] @ FT[b,h]^T  (1024 x 128 x 128)
  gemm_bt<128, 128, 2, 2, 1, 2, 0><<<dim3(1, 8, 128), 256, 0, stream>>>(
      qb, FT, outh, nullptr, outh, 128, 4096, 128, 4096, 4096, 32,
      4194304LL, 128LL, 524288LL, 16384LL, 4194304LL, 128LL, 4194304LL, 128LL);

  // G13: out = outh @ wo^T + bo  (4096 x 4096 x 4096), fp32 (fully overwrites d_out)
  gemm_bt<128, 128, 2, 2, 0, 0, 1><<<dim3(32, 32, 1), 256, 0, stream>>>(
      outh, wo_b, out, bo, nullptr, 4096, 4096, 4096, 4096, 0, 1, Z,Z,Z,Z,Z,Z,Z,Z);
}

// Round 3
// 549.917 us; speedup vs baseline: 1.1863x; 1.1863x over previous
//
#include <hip/hip_runtime.h>
#include <hip/hip_bf16.h>

typedef __attribute__((ext_vector_type(8))) short s8v;
typedef __attribute__((ext_vector_type(4))) float f4v;
typedef __hip_bfloat16 bf16;

// ---- problem constants ----
#define BSZ 4
#define SEQ 1024
#define IDIM 4096
#define RNK 512
#define RPD 64
#define NH 32
#define HD 128
#define BT 4096   // BSZ*SEQ tokens

__device__ __forceinline__ void load_lds16(const bf16* g, bf16* l) {
  __builtin_amdgcn_global_load_lds((const __attribute__((address_space(1))) void*)g,
                                   (__attribute__((address_space(3))) void*)l, 16, 0, 0);
}

// =====================================================================
// 256x256 deep-pipelined bf16 GEMM:  C[m,n] = sum_k A[m,k]*B[n,k] (+bias[n])
// BK=64, 8 waves (2x4), double-buffered swizzled LDS (128 KB), counted vmcnt.
// Grid: 1D, NXT*NYT blocks (must be %8==0). M%256==0, N%256==0, K%64==0.
// =====================================================================
template<int OUT_BF16, int HAS_BIAS>
__global__ __launch_bounds__(512, 2) void gemm256(
    const bf16* __restrict__ A, const bf16* __restrict__ B, void* __restrict__ Cv,
    const float* __restrict__ bias, int K, int lda, int ldb, int ldc, int NXT)
{
  __shared__ bf16 As[2][256 * 64];
  __shared__ bf16 Bs[2][256 * 64];

  // XCD-bijective block swizzle (gridDim.x % 8 == 0)
  int nwg = gridDim.x;
  int orig = blockIdx.x;
  int cpx = nwg >> 3;
  int l = (orig & 7) * cpx + (orig >> 3);
  int tx = l % NXT, ty = l / NXT;
  long long rowBase = (long long)ty * 256;
  long long colBase = (long long)tx * 256;

  int tid = threadIdx.x;
  int lane = tid & 63, wave = tid >> 6;
  int wr = wave >> 2, wc = wave & 3;       // 2 x 4 wave grid; wave tile 128x64
  int lrow = lane & 15, lslot = lane >> 4; // frag row lane / 16B-slot lane

  int NT = K >> 6;

  // stage one K-tile (64 wide) of A and B into buffer bsel, swizzled layout.
  // LDS chunk c (16B) at byte c*16 <-> (r = c>>3, slot s = c&7); source k-chunk = s ^ (r&7).
#define STAGE_TILE(bsel, kt) do {                                              \
    long long k0_ = (long long)(kt) << 6;                                      \
    _Pragma("unroll")                                                          \
    for (int j_ = 0; j_ < 4; ++j_) {                                           \
      int c_ = j_ * 512 + tid; int r_ = c_ >> 3; int s_ = c_ & 7;              \
      load_lds16(A + (rowBase + r_) * lda + k0_ + ((s_ ^ (r_ & 7)) << 3),      \
                 &As[bsel][c_ * 8]);                                           \
    }                                                                          \
    _Pragma("unroll")                                                          \
    for (int j_ = 0; j_ < 4; ++j_) {                                           \
      int c_ = j_ * 512 + tid; int r_ = c_ >> 3; int s_ = c_ & 7;              \
      load_lds16(B + (colBase + r_) * ldb + k0_ + ((s_ ^ (r_ & 7)) << 3),      \
                 &Bs[bsel][c_ * 8]);                                           \
    }                                                                          \
  } while (0)

  // swizzled ds_read of one 16x32 fragment (16B/lane)
  auto rdA = [&](int bsel, int m, int kk) -> s8v {
    int r = wr * 128 + m * 16 + lrow;
    int e = r * 64 + ((((kk << 2) | lslot) ^ (r & 7)) << 3);
    return *(const s8v*)&As[bsel][e];
  };
  auto rdB = [&](int bsel, int n, int kk) -> s8v {
    int r = wc * 64 + n * 16 + lrow;
    int e = r * 64 + ((((kk << 2) | lslot) ^ (r & 7)) << 3);
    return *(const s8v*)&Bs[bsel][e];
  };

  f4v acc[8][4];
  #pragma unroll
  for (int m = 0; m < 8; ++m)
    #pragma unroll
    for (int n = 0; n < 4; ++n) acc[m][n] = {0.f, 0.f, 0.f, 0.f};

  // prologue: stage tiles 0 and 1
  STAGE_TILE(0, 0);
  STAGE_TILE(1, 1);

  for (int t = 0; t < NT; ++t) {
    int cur = t & 1;
    // wait for tile t's 8 loads (tile t+1's 8 may stay in flight)
    if (t < NT - 1) asm volatile("s_waitcnt vmcnt(8)" ::: "memory");
    else            asm volatile("s_waitcnt vmcnt(0)" ::: "memory");
    asm volatile("s_barrier" ::: "memory");

    // B fragments for the whole tile (kept live), A for phase 0
    s8v b0[4], b1[4];
    #pragma unroll
    for (int n = 0; n < 4; ++n) { b0[n] = rdB(cur, n, 0); b1[n] = rdB(cur, n, 1); }

    // phases 0..2 : m-pairs {0,1},{2,3},{4,5}
    #pragma unroll
    for (int p = 0; p < 3; ++p) {
      s8v aA0 = rdA(cur, 2 * p, 0),     aA1 = rdA(cur, 2 * p, 1);
      s8v aB0 = rdA(cur, 2 * p + 1, 0), aB1 = rdA(cur, 2 * p + 1, 1);
      __builtin_amdgcn_s_setprio(1);
      #pragma unroll
      for (int n = 0; n < 4; ++n) {
        acc[2 * p][n]     = __builtin_amdgcn_mfma_f32_16x16x32_bf16(aA0, b0[n], acc[2 * p][n], 0, 0, 0);
        acc[2 * p][n]     = __builtin_amdgcn_mfma_f32_16x16x32_bf16(aA1, b1[n], acc[2 * p][n], 0, 0, 0);
        acc[2 * p + 1][n] = __builtin_amdgcn_mfma_f32_16x16x32_bf16(aB0, b0[n], acc[2 * p + 1][n], 0, 0, 0);
        acc[2 * p + 1][n] = __builtin_amdgcn_mfma_f32_16x16x32_bf16(aB1, b1[n], acc[2 * p + 1][n], 0, 0, 0);
      }
      __builtin_amdgcn_s_setprio(0);
    }

    // phase 3 : m-pair {6,7}; after its ds_reads all reads of tile t are done ->
    // barrier, then burst-stage tile t+2 into this same buffer.
    {
      s8v aA0 = rdA(cur, 6, 0), aA1 = rdA(cur, 6, 1);
      s8v aB0 = rdA(cur, 7, 0), aB1 = rdA(cur, 7, 1);
      asm volatile("s_waitcnt lgkmcnt(0)" ::: "memory");
      asm volatile("s_barrier" ::: "memory");
      if (t + 2 < NT) STAGE_TILE(cur, t + 2);
      __builtin_amdgcn_s_setprio(1);
      #pragma unroll
      for (int n = 0; n < 4; ++n) {
        acc[6][n] = __builtin_amdgcn_mfma_f32_16x16x32_bf16(aA0, b0[n], acc[6][n], 0, 0, 0);
        acc[6][n] = __builtin_amdgcn_mfma_f32_16x16x32_bf16(aA1, b1[n], acc[6][n], 0, 0, 0);
        acc[7][n] = __builtin_amdgcn_mfma_f32_16x16x32_bf16(aB0, b0[n], acc[7][n], 0, 0, 0);
        acc[7][n] = __builtin_amdgcn_mfma_f32_16x16x32_bf16(aB1, b1[n], acc[7][n], 0, 0, 0);
      }
      __builtin_amdgcn_s_setprio(0);
    }
  }
#undef STAGE_TILE

  // epilogue
  float* Cf = (float*)Cv;
  bf16* Cb = (bf16*)Cv;
  int lcol = lane & 15, lr4 = (lane >> 4) * 4;
  #pragma unroll
  for (int m = 0; m < 8; ++m)
    #pragma unroll
    for (int n = 0; n < 4; ++n) {
      long long col = colBase + wc * 64 + n * 16 + lcol;
      float bv_ = HAS_BIAS ? bias[col] : 0.f;
      #pragma unroll
      for (int j = 0; j < 4; ++j) {
        long long row = rowBase + wr * 128 + m * 16 + lr4 + j;
        float v = acc[m][n][j] + bv_;
        if (OUT_BF16) Cb[row * ldc + col] = __float2bfloat16(v);
        else          Cf[row * ldc + col] = v;
      }
    }
}

// =====================================================================
// Generic 128-tile bf16 MFMA GEMM (round-2 baseline, kept for small shapes)
// =====================================================================
template<int BM, int BN, int WTM, int WTN, int OUT_BF16, int ADD_MODE, int HAS_BIAS>
__global__ __launch_bounds__(256) void gemm_bt(
    const bf16* __restrict__ A, const bf16* __restrict__ B, void* __restrict__ Cv,
    const float* __restrict__ bias, const void* __restrict__ addend,
    int K, int lda, int ldb, int ldc, int ldadd, int nz2,
    long long sA1, long long sA2, long long sB1, long long sB2,
    long long sC1, long long sC2, long long sD1, long long sD2)
{
  constexpr int BK = 32;
  constexpr int WM = BM / WTM, WN = BN / WTN;
  constexpr int FM = WM / 16, FN = WN / 16;
  static_assert(WTM * WTN == 4, "4 waves / 256 threads");
  static_assert((BM * BK) % 2048 == 0 && (BN * BK) % 2048 == 0, "staging coverage");
  __shared__ alignas(16) bf16 As[BM * BK];
  __shared__ alignas(16) bf16 Bs[BN * BK];

  int z = blockIdx.z;
  int z1 = z / nz2, z2 = z - z1 * nz2;
  A += z1 * sA1 + z2 * sA2;
  B += z1 * sB1 + z2 * sB2;
  long long coff = z1 * sC1 + z2 * sC2;
  long long doffz = z1 * sD1 + z2 * sD2;

  int tid = threadIdx.x;
  int lane = tid & 63, wave = tid >> 6;
  int wr = wave / WTN, wc = wave % WTN;
  int rowBase = blockIdx.y * BM;
  int colBase = blockIdx.x * BN;

  f4v acc[FM][FN];
  #pragma unroll
  for (int i = 0; i < FM; ++i)
    #pragma unroll
    for (int j = 0; j < FN; ++j) acc[i][j] = {0.f, 0.f, 0.f, 0.f};

  constexpr int A_LOADS = (BM * BK) / 2048;
  constexpr int B_LOADS = (BN * BK) / 2048;
  int lrow = lane & 15, lk = (lane >> 4) * 8;

  for (int k0 = 0; k0 < K; k0 += BK) {
    #pragma unroll
    for (int i = 0; i < A_LOADS; ++i) {
      int e = tid * 8 + i * 2048;
      load_lds16(A + (long long)(rowBase + (e >> 5)) * lda + k0 + (e & 31), &As[e]);
    }
    #pragma unroll
    for (int i = 0; i < B_LOADS; ++i) {
      int e = tid * 8 + i * 2048;
      load_lds16(B + (long long)(colBase + (e >> 5)) * ldb + k0 + (e & 31), &Bs[e]);
    }
    __syncthreads();

    s8v av[FM], bv[FN];
    #pragma unroll
    for (int fm = 0; fm < FM; ++fm)
      av[fm] = *(const s8v*)&As[(wr * WM + fm * 16 + lrow) * BK + lk];
    #pragma unroll
    for (int fn = 0; fn < FN; ++fn)
      bv[fn] = *(const s8v*)&Bs[(wc * WN + fn * 16 + lrow) * BK + lk];
    #pragma unroll
    for (int fm = 0; fm < FM; ++fm)
      #pragma unroll
      for (int fn = 0; fn < FN; ++fn)
        acc[fm][fn] = __builtin_amdgcn_mfma_f32_16x16x32_bf16(av[fm], bv[fn], acc[fm][fn], 0, 0, 0);
    __syncthreads();
  }

  bf16* Cb = (bf16*)Cv;
  float* Cf = (float*)Cv;
  const float* addf = (const float*)addend;
  const bf16* addb = (const bf16*)addend;
  int lcol = lane & 15, lr4 = (lane >> 4) * 4;
  #pragma unroll
  for (int fm = 0; fm < FM; ++fm) {
    #pragma unroll
    for (int fn = 0; fn < FN; ++fn) {
      int col = colBase + wc * WN + fn * 16 + lcol;
      #pragma unroll
      for (int j = 0; j < 4; ++j) {
        int row = rowBase + wr * WM + fm * 16 + lr4 + j;
        float v = acc[fm][fn][j];
        if (HAS_BIAS) v += bias[col];
        if (ADD_MODE == 1) v += addf[doffz + (long long)row * ldadd + col];
        if (ADD_MODE == 2) v += __bfloat162float(addb[doffz + (long long)row * ldadd + col]);
        long long idx = coff + (long long)row * ldc + col;
        if (OUT_BF16) Cb[idx] = __float2bfloat16(v);
        else          Cf[idx] = v;
      }
    }
  }
}

// ---------------- elementwise / helper kernels ----------------

__global__ void cast4(const float* __restrict__ in, bf16* __restrict__ out, int n4) {
  int i = blockIdx.x * 256 + threadIdx.x;
  if (i >= n4) return;
  float4 v = ((const float4*)in)[i];
  union { ushort4 u; bf16 h[4]; } o;
  o.h[0] = __float2bfloat16(v.x); o.h[1] = __float2bfloat16(v.y);
  o.h[2] = __float2bfloat16(v.z); o.h[3] = __float2bfloat16(v.w);
  ((ushort4*)out)[i] = o.u;
}

// 32x32-tile bf16 transpose: in (R x C) -> out (C x R), batched over z
__global__ __launch_bounds__(256) void tr_bf16(const bf16* __restrict__ in, bf16* __restrict__ out,
                                               int R, int C) {
  __shared__ bf16 t[32][33];
  long long zo = (long long)blockIdx.z * R * C;
  int c0 = blockIdx.x * 32, r0 = blockIdx.y * 32;
  int tx = threadIdx.x & 31, ty = threadIdx.x >> 5;   // 32 x 8
  #pragma unroll
  for (int i = 0; i < 32; i += 8)
    t[ty + i][tx] = in[zo + (long long)(r0 + ty + i) * C + (c0 + tx)];
  __syncthreads();
  #pragma unroll
  for (int i = 0; i < 32; i += 8)
    out[zo + (long long)(c0 + ty + i) * R + (r0 + tx)] = t[tx][ty + i];
}

__device__ __forceinline__ float block_sum256(float v) {
  #pragma unroll
  for (int o = 32; o > 0; o >>= 1) v += __shfl_xor(v, o, 64);
  __shared__ float red[4];
  int lane = threadIdx.x & 63, w = threadIdx.x >> 6;
  if (lane == 0) red[w] = v;
  __syncthreads();
  return red[0] + red[1] + red[2] + red[3];
}

// dkv row (len 576 fp32): rmsnorm first 512 -> ckv bf16 ; rope last 64 -> kr bf16
__global__ __launch_bounds__(256) void rms_dkv(const float* __restrict__ dkv,
    const float* __restrict__ w, const float* __restrict__ ch, const float* __restrict__ sh,
    bf16* __restrict__ ckv, bf16* __restrict__ kr) {
  int row = blockIdx.x, t = threadIdx.x;
  const float* xr = dkv + (long long)row * 576;
  float v0 = xr[t], v1 = xr[t + 256];
  float ss = block_sum256(v0 * v0 + v1 * v1);
  float sc = rsqrtf(ss * (1.0f / 512.0f) + 1.1920929e-07f);
  long long o = (long long)row * 512;
  ckv[o + t]       = __float2bfloat16(v0 * sc * w[t]);
  ckv[o + t + 256] = __float2bfloat16(v1 * sc * w[t + 256]);
  if (t < 64) {
    int s = row & (SEQ - 1);
    float a = xr[512 + t], r;
    if (t < 32) r = a * ch[s * 32 + t]      - xr[512 + t + 32] * sh[s * 32 + t];
    else        r = a * ch[s * 32 + t - 32] + xr[512 + t - 32] * sh[s * 32 + t - 32];
    kr[(long long)row * 64 + t] = __float2bfloat16(r);
  }
}

__global__ __launch_bounds__(256) void rms512(const float* __restrict__ in,
    const float* __restrict__ w, bf16* __restrict__ out) {
  int row = blockIdx.x, t = threadIdx.x;
  const float* xr = in + (long long)row * 512;
  float v0 = xr[t], v1 = xr[t + 256];
  float ss = block_sum256(v0 * v0 + v1 * v1);
  float sc = rsqrtf(ss * (1.0f / 512.0f) + 1.1920929e-07f);
  long long o = (long long)row * 512;
  out[o + t]       = __float2bfloat16(v0 * sc * w[t]);
  out[o + t + 256] = __float2bfloat16(v1 * sc * w[t + 256]);
}

__global__ void rope_qr(const float* __restrict__ in, const float* __restrict__ ch,
                        const float* __restrict__ sh, bf16* __restrict__ out) {
  int row = blockIdx.x, t = threadIdx.x;   // 64 threads
  const float* xr = in + (long long)row * 64;
  int s = row & (SEQ - 1);
  float a = xr[t], r;
  if (t < 32) r = a * ch[s * 32 + t]      - xr[t + 32] * sh[s * 32 + t];
  else        r = a * ch[s * 32 + t - 32] + xr[t - 32] * sh[s * 32 + t - 32];
  out[(long long)row * 64 + t] = __float2bfloat16(r);
}

// =====================================================================
extern "C" void kernel_launch(void* const* d_in, const int* in_sizes, int n_in,
                              void* d_out, int out_size, void* d_ws, size_t ws_size,
                              hipStream_t stream) {
  const float* x    = (const float*)d_in[0];
  const float* ch   = (const float*)d_in[1];
  const float* sh   = (const float*)d_in[2];
  const float* mask = (const float*)d_in[3];
  const float* wdkv = (const float*)d_in[4];
  const float* bdkv = (const float*)d_in[5];
  const float* kvnw = (const float*)d_in[6];
  const float* wdq  = (const float*)d_in[7];
  const float* bdq  = (const float*)d_in[8];
  const float* qnw  = (const float*)d_in[9];
  const float* wuq  = (const float*)d_in[10];
  const float* buq  = (const float*)d_in[11];
  const float* wqr  = (const float*)d_in[12];
  const float* bqr  = (const float*)d_in[13];
  const float* wuk  = (const float*)d_in[14];
  const float* wuv  = (const float*)d_in[15];
  const float* wo   = (const float*)d_in[16];
  const float* bo   = (const float*)d_in[17];
  float* out = (float*)d_out;
  (void)in_sizes; (void)n_in; (void)out_size; (void)ws_size;

  // ---------- workspace layout (total ~107 MB) ----------
  char* ws = (char*)d_ws;
  bf16* regionA = (bf16*)(ws);                       // 33,554,432 B : xb then wo_b
  bf16* outh    = (bf16*)(ws + 33554432);            // 33,554,432 B
  bf16* wdkv_b  = (bf16*)(ws + 67108864);            //  4,718,592 B
  bf16* wdq_b   = (bf16*)(ws + 71827456);            //  4,194,304 B
  bf16* wuq_b   = (bf16*)(ws + 76021760);            //  4,194,304 B
  bf16* wqr_b   = (bf16*)(ws + 80216064);            //     65,536 B
  bf16* wuv_b   = (bf16*)(ws + 80281600);            //  4,194,304 B
  bf16* wuk_b   = (bf16*)(ws + 84475904);            //  4,194,304 B
  bf16* mask_b  = (bf16*)(ws + 88670208);            //  2,097,152 B
  char* regionB = ws + 90767360;                     // 20,971,520 B
  float* dkv_f  = (float*)(regionB);                 //  9,437,184 B (phase 1)
  float* cq_pre = (float*)(regionB + 9437184);       //  8,388,608 B (phase 1)
  bf16* Eb      = (bf16*)(regionB);                  // 16,777,216 B (phase 2)
  bf16* FT      = (bf16*)(regionB + 16777216);       //  4,194,304 B (phase 2)

  bf16* xb   = regionA;          // phase 1 of regionA
  bf16* wo_b = regionA;          // phase 2 of regionA (cast after G2)

  // ---------- d_out used as scratch (64 MB); all dead before G13 ----------
  char* ob = (char*)d_out;
  bf16* qb     = (bf16*)(ob);                 // 33,554,432 B
  char* U      = ob + 33554432;
  bf16* ckv    = (bf16*)(U);                  // 4,194,304
  bf16* kr     = (bf16*)(U + 4194304);        //   524,288
  bf16* ckvT   = (bf16*)(U + 4718592);        // 4,194,304
  bf16* krT    = (bf16*)(U + 8912896);        //   524,288
  bf16* cq     = (bf16*)(U + 9437184);        // 4,194,304
  float* qr_pre= (float*)(U + 13631488);      // 1,048,576
  bf16* qr_b   = (bf16*)(U + 14680064);       //   524,288
  bf16* Gm     = (bf16*)(U + 15204352);       // 2,097,152
  bf16* Mt     = (bf16*)(U + 17301504);       //   262,144
  bf16* base_b = (bf16*)(U + 17563648);       // 4,194,304

  long long Z = 0;

  // ---- early casts ----
  cast4<<<dim3(16384), 256, 0, stream>>>(x, xb, 4194304);
  cast4<<<dim3(2304),  256, 0, stream>>>(wdkv, wdkv_b, 589824);
  cast4<<<dim3(2048),  256, 0, stream>>>(wdq, wdq_b, 524288);
  cast4<<<dim3(32),    256, 0, stream>>>(wqr, wqr_b, 8192);
  cast4<<<dim3(1024),  256, 0, stream>>>(mask, mask_b, 262144);

  // G1: dkv = x @ wdkv^T + b   (4096 x 576 x 4096), fp32 out
  gemm_bt<128, 64, 4, 1, 0, 0, 1><<<dim3(9, 32, 1), 256, 0, stream>>>(
      xb, wdkv_b, dkv_f, bdkv, nullptr, 4096, 4096, 4096, 576, 0, 1, Z,Z,Z,Z,Z,Z,Z,Z);
  rms_dkv<<<dim3(BT), 256, 0, stream>>>(dkv_f, kvnw, ch, sh, ckv, kr);
  tr_bf16<<<dim3(16, 32, 4), 256, 0, stream>>>(ckv, ckvT, 1024, 512);
  tr_bf16<<<dim3(2, 32, 4), 256, 0, stream>>>(kr, krT, 1024, 64);

  // G2: cq_pre = x @ wdq^T + b  (4096 x 512 x 4096), fp32   (last read of xb)
  gemm_bt<128, 128, 2, 2, 0, 0, 1><<<dim3(4, 32, 1), 256, 0, stream>>>(
      xb, wdq_b, cq_pre, bdq, nullptr, 4096, 4096, 4096, 512, 0, 1, Z,Z,Z,Z,Z,Z,Z,Z);
  rms512<<<dim3(BT), 256, 0, stream>>>(cq_pre, qnw, cq);

  // ---- late casts (after G2: regionA now free for wo_b) ----
  cast4<<<dim3(2048),  256, 0, stream>>>(wuq, wuq_b, 524288);
  cast4<<<dim3(2048),  256, 0, stream>>>(wuv, wuv_b, 524288);
  cast4<<<dim3(2048),  256, 0, stream>>>(wuk, wuk_b, 524288);
  cast4<<<dim3(16384), 256, 0, stream>>>(wo, wo_b, 4194304);

  // G3: q = cq @ wuq^T + b  (4096 x 4096 x 512), bf16 -> qb  [256-tile pipeline]
  gemm256<1, 1><<<dim3(256), 512, 0, stream>>>(
      cq, wuq_b, qb, buq, 512, 512, 512, 4096, 16);

  // G4: qr_pre = cq @ wqr^T + b  (4096 x 64 x 512), fp32
  gemm_bt<128, 64, 4, 1, 0, 0, 1><<<dim3(1, 32, 1), 256, 0, stream>>>(
      cq, wqr_b, qr_pre, bqr, nullptr, 512, 512, 512, 64, 0, 1, Z,Z,Z,Z,Z,Z,Z,Z);
  rope_qr<<<dim3(BT), 64, 0, stream>>>(qr_pre, ch, sh, qr_b);

  // G6: G[b] = ckvT[b] @ ckvT[b]^T  (512 x 512 x 1024), z = b
  gemm_bt<128, 128, 2, 2, 1, 0, 0><<<dim3(4, 4, 4), 256, 0, stream>>>(
      ckvT, ckvT, Gm, nullptr, nullptr, 1024, 1024, 1024, 512, 0, 1,
      524288LL, Z, 524288LL, Z, 262144LL, Z, Z, Z);

  // G7: Mt[b] = ckvT[b] @ krT[b]^T  (512 x 64 x 1024), z = b
  gemm_bt<128, 64, 4, 1, 1, 0, 0><<<dim3(1, 4, 4), 256, 0, stream>>>(
      ckvT, krT, Mt, nullptr, nullptr, 1024, 1024, 1024, 64, 0, 1,
      524288LL, Z, 65536LL, Z, 32768LL, Z, Z, Z);

  // G8: base[b] = mask @ ckvT[b]^T  (1024 x 512 x 1024), z = b
  gemm_bt<128, 128, 2, 2, 1, 0, 0><<<dim3(4, 8, 4), 256, 0, stream>>>(
      mask_b, ckvT, base_b, nullptr, nullptr, 1024, 1024, 1024, 512, 0, 1,
      Z, Z, 524288LL, Z, 524288LL, Z, Z, Z);

  // G9: base[b] += qr[b] @ Mt[b]^T   (1024 x 512 x 64), in-place addend
  gemm_bt<128, 128, 2, 2, 1, 2, 0><<<dim3(4, 8, 4), 256, 0, stream>>>(
      qr_b, Mt, base_b, nullptr, base_b, 64, 64, 64, 512, 512, 1,
      65536LL, Z, 32768LL, Z, 524288LL, Z, 524288LL, Z);

  // G10: outh = base @ wuv^T  (4096 x 4096 x 512), bf16  [256-tile pipeline]
  gemm256<1, 0><<<dim3(256), 512, 0, stream>>>(
      base_b, wuv_b, outh, nullptr, 512, 512, 512, 4096, 16);

  // E[b,h] = wuv_h @ G[b]^T  (128 x 512 x 512), z = (b,h)   (regionB phase 2)
  gemm_bt<128, 128, 2, 2, 1, 0, 0><<<dim3(4, 1, 128), 256, 0, stream>>>(
      wuv_b, Gm, Eb, nullptr, nullptr, 512, 512, 512, 512, 0, 32,
      Z, 65536LL, 262144LL, Z, 2097152LL, 65536LL, Z, Z);

  // FT[b,h] = E[b,h] @ wuk_h^T  (128 x 128 x 512), z = (b,h)
  gemm_bt<128, 128, 2, 2, 1, 0, 0><<<dim3(1, 1, 128), 256, 0, stream>>>(
      Eb, wuk_b, FT, nullptr, nullptr, 512, 512, 512, 128, 0, 32,
      2097152LL, 65536LL, Z, 65536LL, 524288LL, 16384LL, Z, Z);

  // G12: outh[b,:,h*128:+128] += qb[b,:,h*128:+128] @ FT[b,h]^T  (1024 x 128 x 128)
  gemm_bt<128, 128, 2, 2, 1, 2, 0><<<dim3(1, 8, 128), 256, 0, stream>>>(
      qb, FT, outh, nullptr, outh, 128, 4096, 128, 4096, 4096, 32,
      4194304LL, 128LL, 524288LL, 16384LL, 4194304LL, 128LL, 4194304LL, 128LL);

  // G13: out = outh @ wo^T + bo  (4096 x 4096 x 4096), fp32  [256-tile pipeline]
  gemm256<0, 1><<<dim3(256), 512, 0, stream>>>(
      outh, wo_b, out, bo, 4096, 4096, 4096, 4096, 16);
}